// Round 1
// baseline (181.246 us; speedup 1.0000x reference)
//
#include <hip/hip_runtime.h>

// Segment first/last-occurrence scan over the flattened mask.
// Single block, LDS-resident min/max arrays (n=512 -> 4 KB LDS).
__global__ void scan_minmax(const int* __restrict__ mask, int L, int n,
                            int* __restrict__ first, int* __restrict__ last) {
    extern __shared__ int smem[];
    int* s_first = smem;       // [n]
    int* s_last  = smem + n;   // [n]
    for (int i = threadIdx.x; i < n; i += blockDim.x) {
        s_first[i] = 0x7fffffff;
        s_last[i]  = -1;
    }
    __syncthreads();
    for (int pos = threadIdx.x; pos < L; pos += blockDim.x) {
        int id = mask[pos];
        if (id >= 0 && id < n) {      // ids == n (max) are dropped, like segment_min/max
            atomicMin(&s_first[id], pos);
            atomicMax(&s_last[id], pos);
        }
    }
    __syncthreads();
    for (int i = threadIdx.x; i < n; i += blockDim.x) {
        first[i] = s_first[i];
        last[i]  = s_last[i];
    }
}

// One block per output row i: out[i] = concat(x[first[i]], x[last[i]]),
// row width 2*H floats, moved as float4 (H4 = H/4 float4 per half-row).
__global__ void gather_rows(const float4* __restrict__ x,
                            const int* __restrict__ first,
                            const int* __restrict__ last,
                            float4* __restrict__ out, int H4) {
    int i = blockIdx.x;
    int f = first[i];
    int l = last[i];
    const float4* __restrict__ sf = x + (size_t)f * H4;
    const float4* __restrict__ sl = x + (size_t)l * H4;
    float4* __restrict__ dst = out + (size_t)i * (size_t)(2 * H4);
    for (int t = threadIdx.x; t < H4; t += blockDim.x) {
        dst[t]      = sf[t];
        dst[H4 + t] = sl[t];
    }
}

extern "C" void kernel_launch(void* const* d_in, const int* in_sizes, int n_in,
                              void* d_out, int out_size, void* d_ws, size_t ws_size,
                              hipStream_t stream) {
    const float* x  = (const float*)d_in[0];
    const int* mask = (const int*)d_in[1];   // number_mask (int32 on device)

    const int L = in_sizes[1];           // B*S = 32768
    const int H = in_sizes[0] / L;       // 1024
    const int n = out_size / (2 * H);    // 512 (concat == 1 per setup)

    int* first = (int*)d_ws;             // [n]
    int* last  = first + n;              // [n]

    scan_minmax<<<1, 1024, 2 * n * sizeof(int), stream>>>(mask, L, n, first, last);

    const int H4 = H / 4;                // 256 float4 per half-row
    gather_rows<<<n, 256, 0, stream>>>((const float4*)x, first, last,
                                       (float4*)d_out, H4);
}

// Round 2
// 167.877 us; speedup vs baseline: 1.0796x; 1.0796x over previous
//
#include <hip/hip_runtime.h>

// Fused: each block `seg` scans the whole mask (L2-resident, 128 KB) to find
// the first/last row-major occurrence of id==seg, then gathers
// out[seg] = concat(x[first], x[last]).
__global__ __launch_bounds__(1024) void fused_seg_gather(
    const int4* __restrict__ mask4, const float4* __restrict__ x,
    float4* __restrict__ out, int L4, int H4) {
    const int seg = blockIdx.x;

    int fmin = 0x7fffffff;
    int fmax = -1;
    for (int k = threadIdx.x; k < L4; k += blockDim.x) {
        int4 m = mask4[k];
        int base = k << 2;
        if (m.x == seg) { fmin = min(fmin, base);     fmax = max(fmax, base);     }
        if (m.y == seg) { fmin = min(fmin, base + 1); fmax = max(fmax, base + 1); }
        if (m.z == seg) { fmin = min(fmin, base + 2); fmax = max(fmax, base + 2); }
        if (m.w == seg) { fmin = min(fmin, base + 3); fmax = max(fmax, base + 3); }
    }

    // wave (64-lane) shuffle reduction
    for (int off = 32; off > 0; off >>= 1) {
        fmin = min(fmin, __shfl_down(fmin, off, 64));
        fmax = max(fmax, __shfl_down(fmax, off, 64));
    }
    __shared__ int s_min[16], s_max[16];
    const int wave = threadIdx.x >> 6;
    if ((threadIdx.x & 63) == 0) { s_min[wave] = fmin; s_max[wave] = fmax; }
    __syncthreads();
    const int nwaves = blockDim.x >> 6;
    if (threadIdx.x == 0) {
        int m = s_min[0], M = s_max[0];
        for (int w = 1; w < nwaves; ++w) { m = min(m, s_min[w]); M = max(M, s_max[w]); }
        s_min[0] = m; s_max[0] = M;
    }
    __syncthreads();
    int f = s_min[0];
    int l = s_max[0];
    if (l < 0) { f = 0; l = 0; }  // segment never occurs (not expected here)

    const float4* __restrict__ sf = x + (size_t)f * H4;
    const float4* __restrict__ sl = x + (size_t)l * H4;
    float4* __restrict__ dst = out + (size_t)seg * (size_t)(2 * H4);
    for (int t = threadIdx.x; t < 2 * H4; t += blockDim.x) {
        dst[t] = (t < H4) ? sf[t] : sl[t - H4];
    }
}

extern "C" void kernel_launch(void* const* d_in, const int* in_sizes, int n_in,
                              void* d_out, int out_size, void* d_ws, size_t ws_size,
                              hipStream_t stream) {
    const float* x  = (const float*)d_in[0];
    const int* mask = (const int*)d_in[1];   // number_mask (int32 on device)

    const int L = in_sizes[1];           // B*S = 32768
    const int H = in_sizes[0] / L;       // 1024
    const int n = out_size / (2 * H);    // 512 (concat == 1 per setup)

    const int L4 = L / 4;
    const int H4 = H / 4;

    fused_seg_gather<<<n, 1024, 0, stream>>>((const int4*)mask, (const float4*)x,
                                             (float4*)d_out, L4, H4);
}